// Round 1
// baseline (12045.783 us; speedup 1.0000x reference)
//
#include <hip/hip_runtime.h>
#include <cstdint>
#include <cstddef>

#define N_NODES 50000
#define N_EDGES 800000
#define F_IN_D 100
#define HDIM 128
#define CDIM 10

// ---------------- preprocessing ----------------

__global__ void convert_edges_kernel(const int* __restrict__ ei, int* __restrict__ row32,
                                     int* __restrict__ col32, int E) {
  // Detect int64 vs int32 storage: for int64 (values < 2^31), every high word is 0.
  bool is64 = true;
  for (int i = 0; i < 32; ++i) { if (ei[2 * i + 1] != 0) is64 = false; }
  int e = blockIdx.x * blockDim.x + threadIdx.x;
  if (e < E) {
    if (is64) { row32[e] = ei[2 * e]; col32[e] = ei[2 * (E + e)]; }
    else      { row32[e] = ei[e];     col32[e] = ei[E + e]; }
  }
}

__global__ void deg_kernel(const int* __restrict__ col32, const float* __restrict__ w,
                           float* __restrict__ deg, int E) {
  int e = blockIdx.x * blockDim.x + threadIdx.x;
  if (e < E) atomicAdd(&deg[col32[e]], w[e]);
}

__global__ void dis_kernel(const float* __restrict__ deg, float* __restrict__ dis, int n) {
  int i = blockIdx.x * blockDim.x + threadIdx.x;
  if (i < n) {
    float d = deg[i];
    dis[i] = d > 0.f ? rsqrtf(fmaxf(d, 1e-12f)) : 0.f;
  }
}

__global__ void norm_count_kernel(const int* __restrict__ row32, const int* __restrict__ col32,
                                  const float* __restrict__ w, const float* __restrict__ dis,
                                  float* __restrict__ nrm, int* __restrict__ cnt, int E) {
  int e = blockIdx.x * blockDim.x + threadIdx.x;
  if (e < E) {
    int r = row32[e], c = col32[e];
    nrm[e] = dis[r] * w[e] * dis[c];
    atomicAdd(&cnt[c], 1);
  }
}

__global__ void scan_kernel(const int* __restrict__ cnt, int* __restrict__ ptr,
                            int* __restrict__ pos, int n) {
  __shared__ int sd[256];
  __shared__ int carry;
  int tid = threadIdx.x;
  if (tid == 0) carry = 0;
  __syncthreads();
  for (int base = 0; base < n; base += 256) {
    int i = base + tid;
    int v = (i < n) ? cnt[i] : 0;
    sd[tid] = v;
    __syncthreads();
    for (int offd = 1; offd < 256; offd <<= 1) {
      int t = (tid >= offd) ? sd[tid - offd] : 0;
      __syncthreads();
      sd[tid] += t;
      __syncthreads();
    }
    int excl = sd[tid] - v;
    if (i < n) { int p = carry + excl; ptr[i] = p; pos[i] = p; }
    int total = sd[255];
    __syncthreads();
    if (tid == 0) carry += total;
    __syncthreads();
  }
  if (tid == 0) ptr[n] = carry;
}

__global__ void place_kernel(const int* __restrict__ row32, const int* __restrict__ col32,
                             const float* __restrict__ nrm, int* __restrict__ pos,
                             int* __restrict__ srcs, float* __restrict__ wsrt, int E) {
  int e = blockIdx.x * blockDim.x + threadIdx.x;
  if (e < E) {
    int c = col32[e];
    int slot = atomicAdd(&pos[c], 1);
    srcs[slot] = row32[e];
    wsrt[slot] = nrm[e];
  }
}

// ---------------- propagation (hop) ----------------

template <int DIM>
__global__ void hop_kernel(const float* __restrict__ h, const int* __restrict__ ptr,
                           const int* __restrict__ srcs, const float* __restrict__ wsrt,
                           float* __restrict__ out, int n) {
  int local = threadIdx.x >> 7;           // 2 nodes per 256-thread block
  int f = threadIdx.x & 127;
  int node = blockIdx.x * 2 + local;
  if (node >= n) return;
  if (f >= DIM) return;
  int b = ptr[node], e = ptr[node + 1];
  float acc = 0.f;
  for (int j = b; j < e; ++j) {
    int s = srcs[j];
    float w = wsrt[j];
    acc += w * h[(size_t)s * DIM + f];
  }
  out[(size_t)node * DIM + f] = acc;
}

// d=10 hop with fused add:  out[n][f] = ybuf[n*64 + yOff + f] + sum_e w * z[s*zStride + zOff + f]
__global__ void hop10_kernel(const float* __restrict__ z, int zStride, int zOff,
                             const float* __restrict__ ybuf, int yOff,
                             const int* __restrict__ ptr, const int* __restrict__ srcs,
                             const float* __restrict__ wsrt, float* __restrict__ out, int n) {
  int local = threadIdx.x >> 4;           // 16 nodes per 256-thread block
  int f = threadIdx.x & 15;
  int node = blockIdx.x * 16 + local;
  if (node >= n || f >= CDIM) return;
  float acc = ybuf[(size_t)node * 64 + yOff + f];
  int b = ptr[node], e = ptr[node + 1];
  for (int j = b; j < e; ++j) {
    int s = srcs[j];
    float w = wsrt[j];
    acc += w * z[(size_t)s * zStride + zOff + f];
  }
  out[(size_t)node * CDIM + f] = acc;
}

// ---------------- dense GEMM ----------------
// out[n, c] (+)= sum_k X[n,k] * B[k,c]   (64x64 tile, 256 threads, 4x4 per thread)
// BMODE 0: B[k,c] = W[k*128 + c]                        (W is [K_DIM][128] slice)
// BMODE 1: B[k,c] = W3[(c/10)*K_DIM*10 + k*10 + c%10]   (c<60; 6 hop-matrices concatenated)
template <int K_DIM, int BMODE, bool INIT_B, bool ELU_OUT>
__global__ void gemm_kernel(const float* __restrict__ X, const float* __restrict__ W,
                            const float* __restrict__ bias, float* __restrict__ out,
                            int n, int ostride) {
  __shared__ float xt[32][68];   // [k][node], padded
  __shared__ float bt[32][64];   // [k][col]
  const int tid = threadIdx.x;
  const int tx = tid & 15;       // node group
  const int ty = tid >> 4;       // col group
  const int n0 = blockIdx.x * 64;
  const int c0 = blockIdx.y * 64;
  float acc[4][4];
#pragma unroll
  for (int i = 0; i < 4; ++i)
#pragma unroll
    for (int j = 0; j < 4; ++j) acc[i][j] = 0.f;

  for (int k0 = 0; k0 < K_DIM; k0 += 32) {
#pragma unroll
    for (int i = 0; i < 8; ++i) {
      int idx = tid + i * 256;
      int nl = idx >> 5, kl = idx & 31;
      int nn = n0 + nl, kg = k0 + kl;
      float v = 0.f;
      if (nn < n && kg < K_DIM) v = X[(size_t)nn * K_DIM + kg];
      xt[kl][nl] = v;
    }
#pragma unroll
    for (int i = 0; i < 8; ++i) {
      int idx = tid + i * 256;
      int kl = idx >> 6, cl = idx & 63;
      int kg = k0 + kl, c = c0 + cl;
      float v = 0.f;
      if (BMODE == 0) {
        if (kg < K_DIM) v = W[(size_t)kg * 128 + c];
      } else {
        if (kg < K_DIM && cl < 6 * CDIM)
          v = W[(size_t)(cl / CDIM) * (K_DIM * CDIM) + (size_t)kg * CDIM + (cl % CDIM)];
      }
      bt[kl][cl] = v;
    }
    __syncthreads();
#pragma unroll
    for (int kk = 0; kk < 32; ++kk) {
      float4 xv = *(const float4*)&xt[kk][tx * 4];
      float4 bv = *(const float4*)&bt[kk][ty * 4];
      acc[0][0] += xv.x * bv.x; acc[0][1] += xv.x * bv.y; acc[0][2] += xv.x * bv.z; acc[0][3] += xv.x * bv.w;
      acc[1][0] += xv.y * bv.x; acc[1][1] += xv.y * bv.y; acc[1][2] += xv.y * bv.z; acc[1][3] += xv.y * bv.w;
      acc[2][0] += xv.z * bv.x; acc[2][1] += xv.z * bv.y; acc[2][2] += xv.z * bv.z; acc[2][3] += xv.z * bv.w;
      acc[3][0] += xv.w * bv.x; acc[3][1] += xv.w * bv.y; acc[3][2] += xv.w * bv.z; acc[3][3] += xv.w * bv.w;
    }
    __syncthreads();
  }
#pragma unroll
  for (int i = 0; i < 4; ++i) {
    int nn = n0 + tx * 4 + i;
    if (nn >= n) continue;
#pragma unroll
    for (int j = 0; j < 4; ++j) {
      int c = c0 + ty * 4 + j;
      float r = acc[i][j];
      if (INIT_B) {
        if (BMODE == 0) r += bias[c];
        else if (c < CDIM) r += bias[c];
      } else {
        r += out[(size_t)nn * ostride + c];
      }
      if (ELU_OUT) r = r > 0.f ? r : expm1f(r);
      out[(size_t)nn * ostride + c] = r;
    }
  }
}

// ---------------- host ----------------

extern "C" void kernel_launch(void* const* d_in, const int* in_sizes, int n_in,
                              void* d_out, int out_size, void* d_ws, size_t ws_size,
                              hipStream_t stream) {
  const float* x  = (const float*)d_in[0];
  const int*   ei = (const int*)d_in[1];
  const float* ew = (const float*)d_in[2];
  const float* W1 = (const float*)d_in[3];
  const float* b1 = (const float*)d_in[4];
  const float* W2 = (const float*)d_in[5];
  const float* b2 = (const float*)d_in[6];
  const float* W3 = (const float*)d_in[7];
  const float* b3 = (const float*)d_in[8];
  float* out = (float*)d_out;

  const int N = N_NODES, E = N_EDGES;
  char* base = (char*)d_ws;
  size_t off = 0;
  auto alloc = [&](size_t bytes) -> char* {
    char* p = base + off;
    off += (bytes + 255) & ~(size_t)255;
    return p;
  };
  float* h0   = (float*)alloc((size_t)N * 128 * 4);
  float* h1   = (float*)alloc((size_t)N * 128 * 4);
  float* acc1 = (float*)alloc((size_t)N * 128 * 4);
  float* acc2 = (float*)alloc((size_t)N * 128 * 4);
  int*   ptrA = (int*)alloc((size_t)(N + 1) * 4);
  int*   pos  = (int*)alloc((size_t)N * 4);
  int*   srcs = (int*)alloc((size_t)E * 4);
  float* wsrt = (float*)alloc((size_t)E * 4);

  // Transients overlay h0 (h0 is first written only after preprocessing finishes).
  char* t = (char*)h0;
  int*   row32 = (int*)t;   t += (size_t)E * 4;
  int*   col32 = (int*)t;   t += (size_t)E * 4;
  float* nrm   = (float*)t; t += (size_t)E * 4;
  float* deg   = (float*)t; t += (size_t)N * 4;
  float* dis   = (float*)t; t += (size_t)N * 4;
  int*   cnt   = (int*)t;   t += (size_t)N * 4;

  // Layer-3 buffers overlay h0/h1 (dead by then).
  float* ybuf = (float*)h0;                      // [N][64]: c = k*10+f, k=0..5
  float* z0   = (float*)h1;                      // [N][10]
  float* z1   = (float*)((char*)h1 + (size_t)N * 16 * 4);

  hipMemsetAsync(deg, 0, (size_t)N * 4, stream);
  hipMemsetAsync(cnt, 0, (size_t)N * 4, stream);

  int eb = (E + 255) / 256;
  convert_edges_kernel<<<eb, 256, 0, stream>>>(ei, row32, col32, E);
  deg_kernel<<<eb, 256, 0, stream>>>(col32, ew, deg, E);
  dis_kernel<<<(N + 255) / 256, 256, 0, stream>>>(deg, dis, N);
  norm_count_kernel<<<eb, 256, 0, stream>>>(row32, col32, ew, dis, nrm, cnt, E);
  scan_kernel<<<1, 256, 0, stream>>>(cnt, ptrA, pos, N);
  place_kernel<<<eb, 256, 0, stream>>>(row32, col32, nrm, pos, srcs, wsrt, E);

  dim3 gemmGrid((N + 63) / 64, 2);
  int hopBlocks = (N + 1) / 2;
  float* hbuf[2] = {h0, h1};

  // ---- layer 1: F_IN=100 -> 128, ELU ----
  gemm_kernel<F_IN_D, 0, true, false><<<gemmGrid, 256, 0, stream>>>(x, W1, b1, acc1, N, 128);
  const float* hp = x;
  for (int k = 1; k <= 5; ++k) {
    float* hc = hbuf[(k - 1) & 1];
    hop_kernel<F_IN_D><<<hopBlocks, 256, 0, stream>>>(hp, ptrA, srcs, wsrt, hc, N);
    if (k < 5)
      gemm_kernel<F_IN_D, 0, false, false><<<gemmGrid, 256, 0, stream>>>(hc, W1 + (size_t)k * F_IN_D * 128, b1, acc1, N, 128);
    else
      gemm_kernel<F_IN_D, 0, false, true><<<gemmGrid, 256, 0, stream>>>(hc, W1 + (size_t)k * F_IN_D * 128, b1, acc1, N, 128);
    hp = hc;
  }

  // ---- layer 2: 128 -> 128, ELU ----
  gemm_kernel<HDIM, 0, true, false><<<gemmGrid, 256, 0, stream>>>(acc1, W2, b2, acc2, N, 128);
  hp = acc1;
  for (int k = 1; k <= 5; ++k) {
    float* hc = hbuf[(k - 1) & 1];
    hop_kernel<HDIM><<<hopBlocks, 256, 0, stream>>>(hp, ptrA, srcs, wsrt, hc, N);
    if (k < 5)
      gemm_kernel<HDIM, 0, false, false><<<gemmGrid, 256, 0, stream>>>(hc, W2 + (size_t)k * HDIM * 128, b2, acc2, N, 128);
    else
      gemm_kernel<HDIM, 0, false, true><<<gemmGrid, 256, 0, stream>>>(hc, W2 + (size_t)k * HDIM * 128, b2, acc2, N, 128);
    hp = hc;
  }

  // ---- layer 3: 128 -> 10 via Horner on projected y_k ----
  dim3 g3((N + 63) / 64, 1);
  gemm_kernel<HDIM, 1, true, false><<<g3, 256, 0, stream>>>(acc2, W3, b3, ybuf, N, 64);
  int hb = (N + 15) / 16;
  hop10_kernel<<<hb, 256, 0, stream>>>(ybuf, 64, 50, ybuf, 40, ptrA, srcs, wsrt, z0, N);
  hop10_kernel<<<hb, 256, 0, stream>>>(z0, 10, 0, ybuf, 30, ptrA, srcs, wsrt, z1, N);
  hop10_kernel<<<hb, 256, 0, stream>>>(z1, 10, 0, ybuf, 20, ptrA, srcs, wsrt, z0, N);
  hop10_kernel<<<hb, 256, 0, stream>>>(z0, 10, 0, ybuf, 10, ptrA, srcs, wsrt, z1, N);
  hop10_kernel<<<hb, 256, 0, stream>>>(z1, 10, 0, ybuf, 0, ptrA, srcs, wsrt, out, N);

  (void)in_sizes; (void)n_in; (void)out_size; (void)ws_size;
}